// Round 5
// baseline (618.851 us; speedup 1.0000x reference)
//
#include <hip/hip_runtime.h>
#include <stdint.h>

#define BATCH 16384
#define IN_DIM 1024
#define HDIM 4096

typedef _Float16 f16x8 __attribute__((ext_vector_type(8)));
typedef short short8 __attribute__((ext_vector_type(8)));
typedef float f32x16 __attribute__((ext_vector_type(16)));
typedef int i32x4 __attribute__((ext_vector_type(4)));
typedef int i32x16 __attribute__((ext_vector_type(16)));

typedef const __attribute__((address_space(1))) void* gas_ptr;
typedef __attribute__((address_space(3))) void* las_ptr;

__device__ __forceinline__ void async_copy16(const void* g, void* l) {
  __builtin_amdgcn_global_load_lds((gas_ptr)g, (las_ptr)l, 16, 0, 0);
}

#define FENCE asm volatile("" ::: "memory")
#define BARRIER do { FENCE; __builtin_amdgcn_s_barrier(); FENCE; } while (0)
// Counted waits + scheduler pin (rule #18).
#define WAIT_LGKM(N) do { asm volatile("s_waitcnt lgkmcnt(" #N ")" ::: "memory"); \
                          __builtin_amdgcn_sched_barrier(0); } while (0)
#define WAIT_VM(N)   do { asm volatile("s_waitcnt vmcnt(" #N ")" ::: "memory");   \
                          __builtin_amdgcn_sched_barrier(0); } while (0)

// ---------------- prep kernels (unchanged) ----------------

__global__ void cvt_x_f16_kernel(const float* __restrict__ in,
                                 unsigned short* __restrict__ out, int n4) {
  int i = blockIdx.x * blockDim.x + threadIdx.x;
  if (i < n4) {
    const float4 v = ((const float4*)in)[i];
    ushort4 o;
    o.x = __builtin_bit_cast(unsigned short, (_Float16)v.x);
    o.y = __builtin_bit_cast(unsigned short, (_Float16)v.y);
    o.z = __builtin_bit_cast(unsigned short, (_Float16)v.z);
    o.w = __builtin_bit_cast(unsigned short, (_Float16)v.w);
    ((ushort4*)out)[i] = o;
  }
}

__global__ void cvt_s_kernel(const int* __restrict__ s1, unsigned short* __restrict__ o1, int n1_4,
                             const int* __restrict__ s2, unsigned int* __restrict__ o2, int n2_4) {
  int i = blockIdx.x * blockDim.x + threadIdx.x;
  if (i < n1_4) {
    const int4 v = ((const int4*)s1)[i];
    ushort4 o;
    o.x = __builtin_bit_cast(unsigned short, (_Float16)(float)v.x);
    o.y = __builtin_bit_cast(unsigned short, (_Float16)(float)v.y);
    o.z = __builtin_bit_cast(unsigned short, (_Float16)(float)v.z);
    o.w = __builtin_bit_cast(unsigned short, (_Float16)(float)v.w);
    ((ushort4*)o1)[i] = o;
  } else if (i < n1_4 + n2_4) {
    const int j = i - n1_4;
    const int4 v = ((const int4*)s2)[j];
    o2[j] = (v.x & 0xffu) | ((v.y & 0xffu) << 8) | ((v.z & 0xffu) << 16) | ((v.w & 0xffu) << 24);
  }
}

// scale1 = max(softplus(ls1),1e-4); scale2 = max(softplus(ls2),1e-4)/127
// out[i] = b_out[0] for ALL out_size rows (launch covers max(out_size, 2*HDIM)).
__global__ void scales_init_kernel(const float* __restrict__ ls1, float* __restrict__ s1,
                                   const float* __restrict__ ls2, float* __restrict__ s2,
                                   const float* __restrict__ b_out, float* __restrict__ out,
                                   int out_n) {
  int i = blockIdx.x * blockDim.x + threadIdx.x;
  if (i < out_n) out[i] = b_out[0];
  if (i < HDIM) {
    float l = ls1[i];
    float sp = (l > 20.0f) ? l : log1pf(expf(l));
    s1[i] = fmaxf(sp, 1e-4f);
  } else if (i < 2 * HDIM) {
    float l = ls2[i - HDIM];
    float sp = (l > 20.0f) ? l : log1pf(expf(l));
    s2[i - HDIM] = fmaxf(sp, 1e-4f) * (1.0f / 127.0f);
  }
}

// ---------------- GEMM1 (f16 MFMA, 256x256, 8 waves @ 128x64) --------------
// r5: latency-bound diagnosis (r3/r4 ran LDS at 26 B/cyc vs 85+ available).
// Fixes: (1) 2 waves/SIMD (TLP overlap, m114) with 128x64 wave-tiles;
// (2) T4 counted vmcnt(8) -- stage issued at TILE TOP, consumer-wait one full
// tile (~2400 cyc) later, never vmcnt(0) in loop; (3) 2 barriers/tile only;
// (4) counted-lgkm register-dbuf inner pipeline; (5) setprio (meaningful at
// 2 waves/SIMD). LDS: 2 x (A 32KB + B 32KB) = 128 KB dynamic.
// Barrier/race discipline: end-of-tile barrier (all waves' reads consumed
// pre-barrier) precedes next tile's stage into the buffer being retired.

__global__ __launch_bounds__(512, 2)
void gemm1_kernel(const unsigned short* __restrict__ A,
                  const unsigned short* __restrict__ B,
                  const float* __restrict__ scale,
                  const float* __restrict__ bias,
                  signed char* __restrict__ Hout) {
  constexpr int K = IN_DIM;
  extern __shared__ __align__(16) char smem[];
  unsigned short* const S = (unsigned short*)smem;  // As[2]: 0,16384  Bs[2]: 32768,49152 (halfs)

  const int tid = threadIdx.x;
  const int wave = tid >> 6;
  const int lane = tid & 63;
  const int r31 = lane & 31;
  const int half = lane >> 5;
  const int wm = wave >> 2;   // 0..1 -> 128 rows
  const int wn = wave & 3;    // 0..3 -> 64 cols
  const int row0 = blockIdx.y * 256;
  const int col0 = blockIdx.x * 256;

  f32x16 acc[4][2];
#pragma unroll
  for (int i = 0; i < 4; ++i)
#pragma unroll
    for (int j = 0; j < 2; ++j)
#pragma unroll
      for (int r = 0; r < 16; ++r) acc[i][j][r] = 0.0f;

  const unsigned short* Ab = A + (size_t)row0 * K;
  const unsigned short* Bb = B + (size_t)col0 * K;

  // 8 gload_lds per thread per tile (4 A rounds + 4 B rounds, 512 thr x 16 B).
  auto stage = [&](int buf, int k0) {
    unsigned short* As = S + buf * 16384;
    unsigned short* Bs = S + 32768 + buf * 16384;
#pragma unroll
    for (int rd = 0; rd < 4; ++rd) {
      const int p = rd * 512 + tid;
      const int r = p >> 3;
      const int c = (p & 7) ^ (r & 7);
      async_copy16(Ab + (size_t)r * K + k0 + c * 8, &As[(rd * 512 + wave * 64) * 8]);
    }
#pragma unroll
    for (int rd = 0; rd < 4; ++rd) {
      const int p = rd * 512 + tid;
      const int r = p >> 3;
      const int c = (p & 7) ^ (r & 7);
      async_copy16(Bb + (size_t)r * K + k0 + c * 8, &Bs[(rd * 512 + wave * 64) * 8]);
    }
  };

// 6 ds_read_b128 per set (4 A + 2 B). row=lane&31, k=s*16+half*8+e -> chunk
// c=s*2+half; slot cp = c ^ (row&7).
#define G1_LOAD(SET, S_)                                                     \
  { const int c = (S_) * 2 + half;                                           \
    _Pragma("unroll") for (int i = 0; i < 4; ++i) {                          \
      const int ar = wm * 128 + i * 32 + r31;                                \
      const int cp = c ^ (ar & 7);                                           \
      aF[SET][i] = __builtin_bit_cast(f16x8, *(const short8*)&As[ar * 64 + cp * 8]); \
    }                                                                        \
    _Pragma("unroll") for (int j = 0; j < 2; ++j) {                          \
      const int br = wn * 64 + j * 32 + r31;                                 \
      const int cq = c ^ (br & 7);                                           \
      bF[SET][j] = __builtin_bit_cast(f16x8, *(const short8*)&Bs[br * 64 + cq * 8]); \
    } }
#define G1_MMA(SET)                                                          \
  __builtin_amdgcn_s_setprio(1);                                             \
  _Pragma("unroll") for (int i = 0; i < 4; ++i)                              \
    _Pragma("unroll") for (int j = 0; j < 2; ++j)                            \
      acc[i][j] = __builtin_amdgcn_mfma_f32_32x32x16_f16(aF[SET][i], bF[SET][j], acc[i][j], 0, 0, 0); \
  __builtin_amdgcn_s_setprio(0);

  constexpr int NT = K / 64;  // 16
  stage(0, 0);
  WAIT_VM(0);
  BARRIER;

  for (int t = 0; t < NT; ++t) {
    const unsigned short* As = S + (t & 1) * 16384;
    const unsigned short* Bs = S + 32768 + (t & 1) * 16384;
    // Stage t+1 at tile top (post end-barrier of t-1 => its buffer is free);
    // counted wait: own 8 of tile t complete, t+1's 8 stay in flight.
    if (t + 1 < NT) {
      stage((t + 1) & 1, (t + 1) * 64);
      WAIT_VM(8);
    } else {
      WAIT_VM(0);
    }
    BARRIER;  // all waves' tile-t DMA landed

    f16x8 aF[2][4], bF[2][2];
    G1_LOAD(0, 0)
    FENCE;
    G1_LOAD(1, 1)
    WAIT_LGKM(6);   // set0 ready; set1 in flight under MMA
    G1_MMA(0)
    G1_LOAD(0, 2)
    WAIT_LGKM(6);   // set1 ready; set2 in flight
    G1_MMA(1)
    G1_LOAD(1, 3)
    WAIT_LGKM(6);   // set2 ready; set3 in flight
    G1_MMA(0)
    WAIT_LGKM(0);
    G1_MMA(1)
    BARRIER;  // all waves done reading buf[t]; next stage may overwrite it
  }
#undef G1_LOAD
#undef G1_MMA

  // C/D 32x32 layout: col = lane&31, row = (reg&3)+8*(reg>>2)+4*(lane>>5)
#pragma unroll
  for (int j = 0; j < 2; ++j) {
    const int col = col0 + wn * 64 + j * 32 + r31;
    const float sc = scale[col];
    const float bs = bias[col];
#pragma unroll
    for (int i = 0; i < 4; ++i) {
      const int rbase = row0 + wm * 128 + i * 32 + 4 * half;
#pragma unroll
      for (int r = 0; r < 16; ++r) {
        const int row = rbase + (r & 3) + 8 * (r >> 2);
        float v = fminf(fmaxf(acc[i][j][r] * sc + bs, -1.0f), 1.0f);
        Hout[(size_t)row * HDIM + col] = (signed char)(int)rintf(v * 127.0f);
      }
    }
  }
}

// ---------------- GEMM2 (i8 MFMA, 256x256, 8 waves @ 128x64) ---------------
// A: h1_i8 [M][4096], B: state2_i8 [4096][4096] (exact ternary). BK=128 B.
// Same r5 schedule as gemm1; mfma_i32_32x32x32_i8 exact i32 accumulation;
// fused OUT_DIM=1 head epilogue.

__global__ __launch_bounds__(512, 2)
void gemm2_kernel(const signed char* __restrict__ A,
                  const signed char* __restrict__ B,
                  const float* __restrict__ scale,   // softplus/127
                  const float* __restrict__ bias,
                  const float* __restrict__ w_out,
                  float* __restrict__ out) {
  constexpr int K = HDIM;
  extern __shared__ __align__(16) char smem[];
  signed char* const S = (signed char*)smem;  // As[2]: 0,32768  Bs[2]: 65536,98304 (bytes)

  const int tid = threadIdx.x;
  const int wave = tid >> 6;
  const int lane = tid & 63;
  const int r31 = lane & 31;
  const int half = lane >> 5;
  const int wm = wave >> 2;
  const int wn = wave & 3;
  const int row0 = blockIdx.y * 256;
  const int col0 = blockIdx.x * 256;

  i32x16 acc[4][2];
#pragma unroll
  for (int i = 0; i < 4; ++i)
#pragma unroll
    for (int j = 0; j < 2; ++j)
#pragma unroll
      for (int r = 0; r < 16; ++r) acc[i][j][r] = 0;

  const signed char* Ab = A + (size_t)row0 * K;
  const signed char* Bb = B + (size_t)col0 * K;

  auto stage = [&](int buf, int k0) {
    signed char* As = S + buf * 32768;
    signed char* Bs = S + 65536 + buf * 32768;
#pragma unroll
    for (int rd = 0; rd < 4; ++rd) {
      const int p = rd * 512 + tid;
      const int r = p >> 3;
      const int c = (p & 7) ^ (r & 7);
      async_copy16(Ab + (size_t)r * K + k0 + c * 16, &As[(rd * 512 + wave * 64) * 16]);
    }
#pragma unroll
    for (int rd = 0; rd < 4; ++rd) {
      const int p = rd * 512 + tid;
      const int r = p >> 3;
      const int c = (p & 7) ^ (r & 7);
      async_copy16(Bb + (size_t)r * K + k0 + c * 16, &Bs[(rd * 512 + wave * 64) * 16]);
    }
  };

// k-step S_: row = lane&31, k = s*32 + half*16 + e -> chunk c = s*2+half
#define G2_LOAD(SET, S_)                                                     \
  { const int c = (S_) * 2 + half;                                           \
    _Pragma("unroll") for (int i = 0; i < 4; ++i) {                          \
      const int ar = wm * 128 + i * 32 + r31;                                \
      const int cp = c ^ (ar & 7);                                           \
      aF[SET][i] = *(const i32x4*)&As[ar * 128 + cp * 16];                   \
    }                                                                        \
    _Pragma("unroll") for (int j = 0; j < 2; ++j) {                          \
      const int br = wn * 64 + j * 32 + r31;                                 \
      const int cq = c ^ (br & 7);                                           \
      bF[SET][j] = *(const i32x4*)&Bs[br * 128 + cq * 16];                   \
    } }
#define G2_MMA(SET)                                                          \
  __builtin_amdgcn_s_setprio(1);                                             \
  _Pragma("unroll") for (int i = 0; i < 4; ++i)                              \
    _Pragma("unroll") for (int j = 0; j < 2; ++j)                            \
      acc[i][j] = __builtin_amdgcn_mfma_i32_32x32x32_i8(aF[SET][i], bF[SET][j], acc[i][j], 0, 0, 0); \
  __builtin_amdgcn_s_setprio(0);

  constexpr int NT = K / 128;  // 32
  stage(0, 0);
  WAIT_VM(0);
  BARRIER;

  for (int t = 0; t < NT; ++t) {
    const signed char* As = S + (t & 1) * 32768;
    const signed char* Bs = S + 65536 + (t & 1) * 32768;
    if (t + 1 < NT) {
      stage((t + 1) & 1, (t + 1) * 128);
      WAIT_VM(8);
    } else {
      WAIT_VM(0);
    }
    BARRIER;

    i32x4 aF[2][4], bF[2][2];
    G2_LOAD(0, 0)
    FENCE;
    G2_LOAD(1, 1)
    WAIT_LGKM(6);
    G2_MMA(0)
    G2_LOAD(0, 2)
    WAIT_LGKM(6);
    G2_MMA(1)
    G2_LOAD(1, 3)
    WAIT_LGKM(6);
    G2_MMA(0)
    WAIT_LGKM(0);
    G2_MMA(1)
    BARRIER;
  }
#undef G2_LOAD
#undef G2_MMA

  // Fused head: out[row] += sum_col clip(acc*sc+bs)*w_out[col]
#pragma unroll
  for (int i = 0; i < 4; ++i) {
    float rs[16];
#pragma unroll
    for (int r = 0; r < 16; ++r) rs[r] = 0.0f;
#pragma unroll
    for (int j = 0; j < 2; ++j) {
      const int col = col0 + wn * 64 + j * 32 + r31;
      const float sc = scale[col];
      const float bs = bias[col];
      const float w = w_out[col];
#pragma unroll
      for (int r = 0; r < 16; ++r) {
        float v = fminf(fmaxf((float)acc[i][j][r] * sc + bs, -1.0f), 1.0f);
        rs[r] += v * w;
      }
    }
#pragma unroll
    for (int off = 1; off < 32; off <<= 1)
#pragma unroll
      for (int r = 0; r < 16; ++r)
        rs[r] += __shfl_xor(rs[r], off, 64);
    if (r31 == 0) {
      const int rbase = row0 + wm * 128 + i * 32 + 4 * half;
#pragma unroll
      for (int r = 0; r < 16; ++r)
        atomicAdd(&out[rbase + (r & 3) + 8 * (r >> 2)], rs[r]);
    }
  }
}

// ---------------- launch ----------------

extern "C" void kernel_launch(void* const* d_in, const int* in_sizes, int n_in,
                              void* d_out, int out_size, void* d_ws, size_t ws_size,
                              hipStream_t stream) {
  (void)in_sizes; (void)n_in; (void)ws_size;
  const float* x          = (const float*)d_in[0];
  const int*   state1     = (const int*)d_in[1];
  const float* log_scale1 = (const float*)d_in[2];
  const float* bias1      = (const float*)d_in[3];
  const int*   state2     = (const int*)d_in[4];
  const float* log_scale2 = (const float*)d_in[5];
  const float* bias2      = (const float*)d_in[6];
  const float* w_out      = (const float*)d_in[7];
  const float* b_out      = (const float*)d_in[8];
  float* out = (float*)d_out;

  // One-time: both GEMMs need 128 KB dynamic LDS (> default 64 KB cap).
  static int lds_attr_done = 0;
  if (!lds_attr_done) {
    hipFuncSetAttribute((const void*)gemm1_kernel,
                        hipFuncAttributeMaxDynamicSharedMemorySize, 131072);
    hipFuncSetAttribute((const void*)gemm2_kernel,
                        hipFuncAttributeMaxDynamicSharedMemorySize, 131072);
    lds_attr_done = 1;
  }

  char* ws = (char*)d_ws;
  unsigned short* xh  = (unsigned short*)ws; ws += (size_t)BATCH * IN_DIM * 2;  // 32 MB
  unsigned short* s1h = (unsigned short*)ws; ws += (size_t)HDIM * IN_DIM * 2;   // 8 MB
  signed char*    s2q = (signed char*)ws;    ws += (size_t)HDIM * HDIM;         // 16 MB
  signed char*    h1q = (signed char*)ws;    ws += (size_t)BATCH * HDIM;        // 64 MB
  float* scale1 = (float*)ws; ws += HDIM * sizeof(float);
  float* scale2 = (float*)ws; ws += HDIM * sizeof(float);

  const int nx4 = BATCH * IN_DIM / 4;
  const int n1_4 = HDIM * IN_DIM / 4;
  const int n2_4 = HDIM * HDIM / 4;

  cvt_x_f16_kernel<<<(nx4 + 255) / 256, 256, 0, stream>>>(x, xh, nx4);
  cvt_s_kernel<<<(n1_4 + n2_4 + 255) / 256, 256, 0, stream>>>(
      state1, s1h, n1_4, state2, (unsigned int*)s2q, n2_4);
  const int init_n = (out_size > 2 * HDIM) ? out_size : 2 * HDIM;
  scales_init_kernel<<<(init_n + 255) / 256, 256, 0, stream>>>(
      log_scale1, scale1, log_scale2, scale2, b_out, out, out_size);

  dim3 grid(HDIM / 256, BATCH / 256);  // 16 x 64
  gemm1_kernel<<<grid, 512, 131072, stream>>>(xh, s1h, scale1, bias1, h1q);
  gemm2_kernel<<<grid, 512, 131072, stream>>>(h1q, s2q, scale2, bias2, w_out, out);
}

// Round 8
// 547.122 us; speedup vs baseline: 1.1311x; 1.1311x over previous
//
#include <hip/hip_runtime.h>
#include <stdint.h>

#define BATCH 16384
#define IN_DIM 1024
#define HDIM 4096
#define K1 (2 * IN_DIM)  // dual-plane K for gemm1: [a | b] concatenated

// r8 dual-plane x quantization constants. a = rint(16x) (range +-7.97 sigma
// via combined planes -> ZERO clipping, the r6/r7 failure mode); b =
// rint(127*(16x - a)) in [-64,64]. x ~= (127a+b)/2032, rep err <= 2.5e-4.
#define XSTEP 16.0f
#define XDIV  2032.0f  // 127*16

typedef int i32x4 __attribute__((ext_vector_type(4)));
typedef int i32x16 __attribute__((ext_vector_type(16)));

typedef const __attribute__((address_space(1))) void* gas_ptr;
typedef __attribute__((address_space(3))) void* las_ptr;

__device__ __forceinline__ void async_copy16(const void* g, void* l) {
  __builtin_amdgcn_global_load_lds((gas_ptr)g, (las_ptr)l, 16, 0, 0);
}

#define FENCE asm volatile("" ::: "memory")
#define BARRIER do { FENCE; __builtin_amdgcn_s_barrier(); FENCE; } while (0)
#define WAIT_LGKM(N) do { asm volatile("s_waitcnt lgkmcnt(" #N ")" ::: "memory"); \
                          __builtin_amdgcn_sched_barrier(0); } while (0)

// ---------------- prep kernels ----------------

// A' layout [M][2048] i8: row m = [a(k=0..1023) | b(k=0..1023)].
// r7 POST-MORTEM: step 32 clamped x at 3.97 sigma; the ~1200 clipped tail
// samples (worst 5.5 sigma, err 1.47) produced the 1.07e-2 absmax
// (sqrt(614)*1.47/32*0.009 = 1.0e-2, matches). Step 16 extends range to
// 7.97 sigma -> no clips; rounding (2.5e-4) is at f16-path parity.
__global__ void cvt_x_dual_kernel(const float* __restrict__ in,
                                  unsigned int* __restrict__ outA, int n4) {
  int i = blockIdx.x * blockDim.x + threadIdx.x;
  if (i < n4) {
    const float4 v = ((const float4*)in)[i];
    const int m = i >> 8;       // 256 groups-of-4 per 1024-wide row
    const int g = i & 255;
    int a[4], b[4];
    const float xs[4] = {v.x, v.y, v.z, v.w};
#pragma unroll
    for (int t = 0; t < 4; ++t) {
      const float u = xs[t] * XSTEP;
      const float af = rintf(fminf(fmaxf(u, -127.0f), 127.0f));
      float bf = rintf((u - af) * 127.0f);
      bf = fminf(fmaxf(bf, -127.0f), 127.0f);
      a[t] = (int)af;
      b[t] = (int)bf;
    }
    outA[m * 512 + g] =
        (a[0] & 0xffu) | ((a[1] & 0xffu) << 8) | ((a[2] & 0xffu) << 16) | ((a[3] & 0xffu) << 24);
    outA[m * 512 + 256 + g] =
        (b[0] & 0xffu) | ((b[1] & 0xffu) << 8) | ((b[2] & 0xffu) << 16) | ((b[3] & 0xffu) << 24);
  }
}

// state1 -> B' [4096][2048] i8 = [127*s | s] (exact: 127*ternary in {0,+-127});
// state2 -> packed i8 (exact ternary).
__global__ void cvt_s_dual_kernel(const int* __restrict__ s1, unsigned int* __restrict__ o1, int n1_4,
                                  const int* __restrict__ s2, unsigned int* __restrict__ o2, int n2_4) {
  int i = blockIdx.x * blockDim.x + threadIdx.x;
  if (i < n1_4) {
    const int4 v = ((const int4*)s1)[i];
    const int n = i >> 8;
    const int g = i & 255;
    const int h0 = 127 * v.x, h1 = 127 * v.y, h2 = 127 * v.z, h3 = 127 * v.w;
    o1[n * 512 + g] =
        (h0 & 0xffu) | ((h1 & 0xffu) << 8) | ((h2 & 0xffu) << 16) | ((h3 & 0xffu) << 24);
    o1[n * 512 + 256 + g] =
        (v.x & 0xffu) | ((v.y & 0xffu) << 8) | ((v.z & 0xffu) << 16) | ((v.w & 0xffu) << 24);
  } else if (i < n1_4 + n2_4) {
    const int j = i - n1_4;
    const int4 v = ((const int4*)s2)[j];
    o2[j] = (v.x & 0xffu) | ((v.y & 0xffu) << 8) | ((v.z & 0xffu) << 16) | ((v.w & 0xffu) << 24);
  }
}

// scale1 = max(softplus(ls1),1e-4)/2032 (dual-plane dequant folded in)
// scale2 = max(softplus(ls2),1e-4)/127  (h1-i8 dequant folded in)
// out[i] = b_out[0] for ALL out_size rows (launch covers max(out_size, 2*HDIM)).
__global__ void scales_init_kernel(const float* __restrict__ ls1, float* __restrict__ s1,
                                   const float* __restrict__ ls2, float* __restrict__ s2,
                                   const float* __restrict__ b_out, float* __restrict__ out,
                                   int out_n) {
  int i = blockIdx.x * blockDim.x + threadIdx.x;
  if (i < out_n) out[i] = b_out[0];
  if (i < HDIM) {
    float l = ls1[i];
    float sp = (l > 20.0f) ? l : log1pf(expf(l));
    s1[i] = fmaxf(sp, 1e-4f) * (1.0f / XDIV);
  } else if (i < 2 * HDIM) {
    float l = ls2[i - HDIM];
    float sp = (l > 20.0f) ? l : log1pf(expf(l));
    s2[i - HDIM] = fmaxf(sp, 1e-4f) * (1.0f / 127.0f);
  }
}

// T1 bijective XCD swizzle (1024 blocks, 1024%8==0): each XCD's temporally
// consecutive blocks share one A row-panel -> L2-resident staging sources.
__device__ __forceinline__ void swizzle_bid(int& bx, int& by) {
  const int orig = blockIdx.y * 16 + blockIdx.x;
  const int swz = (orig & 7) * 128 + (orig >> 3);
  bx = swz & 15;
  by = swz >> 4;
}

// ---------------- GEMM1 (i8 MFMA, K=2048 dual-plane, r4 structure) ---------
// A: [a|b]_i8 [M][2048], B: [127*state1|state1]_i8 [4096][2048]. BK=128,
// NT=16, 4 waves @ 128x128, counted-lgkm register-dbuf pipeline, mid-tile
// staging, single vmcnt(0)+barrier per tile (r4-proven schedule verbatim).
// Epilogue: Hout = rint(127*clip(acc*s1/2032 + b1)) -> i8 for gemm2.

__global__ __launch_bounds__(256, 1)
void gemm1_kernel(const signed char* __restrict__ A,
                  const signed char* __restrict__ B,
                  const float* __restrict__ scale,   // softplus/2032
                  const float* __restrict__ bias,
                  signed char* __restrict__ Hout) {
  constexpr int K = K1;  // 2048
  extern __shared__ __align__(16) char smem[];
  signed char* const S = (signed char*)smem;  // As[2]: 0,32768  Bs[2]: 65536,98304

  const int tid = threadIdx.x;
  const int wave = tid >> 6;
  const int lane = tid & 63;
  const int r31 = lane & 31;
  const int half = lane >> 5;
  const int wm = wave >> 1;
  const int wn = wave & 1;
  int bx, by;
  swizzle_bid(bx, by);
  const int row0 = by * 256;
  const int col0 = bx * 256;

  i32x16 acc[4][4];
#pragma unroll
  for (int i = 0; i < 4; ++i)
#pragma unroll
    for (int j = 0; j < 4; ++j)
#pragma unroll
      for (int r = 0; r < 16; ++r) acc[i][j][r] = 0;

  const signed char* Ab = A + (size_t)row0 * K;
  const signed char* Bb = B + (size_t)col0 * K;

  auto stageA = [&](int buf, int k0) {
    signed char* As = S + buf * 32768;
#pragma unroll
    for (int rd = 0; rd < 8; ++rd) {
      const int p = rd * 256 + tid;
      const int r = p >> 3;
      const int c = (p & 7) ^ (r & 7);
      async_copy16(Ab + (size_t)r * K + k0 + c * 16, &As[(rd * 256 + wave * 64) * 16]);
    }
  };
  auto stageB = [&](int buf, int k0) {
    signed char* Bs = S + 65536 + buf * 32768;
#pragma unroll
    for (int rd = 0; rd < 8; ++rd) {
      const int p = rd * 256 + tid;
      const int r = p >> 3;
      const int c = (p & 7) ^ (r & 7);
      async_copy16(Bb + (size_t)r * K + k0 + c * 16, &Bs[(rd * 256 + wave * 64) * 16]);
    }
  };

#define G1_LOAD(SET, S_)                                                     \
  { const int c = (S_) * 2 + half;                                           \
    _Pragma("unroll") for (int i = 0; i < 4; ++i) {                          \
      const int ar = wm * 128 + i * 32 + r31;                                \
      const int cp = c ^ (ar & 7);                                           \
      aF[SET][i] = *(const i32x4*)&As[ar * 128 + cp * 16];                   \
      const int br = wn * 128 + i * 32 + r31;                                \
      const int cq = c ^ (br & 7);                                           \
      bF[SET][i] = *(const i32x4*)&Bs[br * 128 + cq * 16];                   \
    } }
#define G1_MMA(SET)                                                          \
  _Pragma("unroll") for (int i = 0; i < 4; ++i)                              \
    _Pragma("unroll") for (int j = 0; j < 4; ++j)                            \
      acc[i][j] = __builtin_amdgcn_mfma_i32_32x32x32_i8(aF[SET][i], bF[SET][j], acc[i][j], 0, 0, 0);

  constexpr int NT = K / 128;  // 16
  stageA(0, 0);
  stageB(0, 0);
  asm volatile("s_waitcnt vmcnt(0)" ::: "memory");
  BARRIER;

  for (int t = 0; t < NT; ++t) {
    const signed char* As = S + (t & 1) * 32768;
    const signed char* Bs = S + 65536 + (t & 1) * 32768;
    const int nb = (t + 1) & 1;
    const int nk0 = (t + 1) * 128;
    const bool pf = (t + 1 < NT);
    i32x4 aF[2][4], bF[2][4];

    G1_LOAD(0, 0)
    FENCE;
    G1_LOAD(1, 1)
    WAIT_LGKM(8);
    G1_MMA(0)
    if (pf) stageA(nb, nk0);
    G1_LOAD(0, 2)
    WAIT_LGKM(8);
    G1_MMA(1)
    if (pf) stageB(nb, nk0);
    G1_LOAD(1, 3)
    WAIT_LGKM(8);
    G1_MMA(0)
    WAIT_LGKM(0);
    G1_MMA(1)
    asm volatile("s_waitcnt vmcnt(0)" ::: "memory");
    BARRIER;
  }
#undef G1_LOAD
#undef G1_MMA

  // C/D 32x32 layout: col = lane&31, row = (reg&3)+8*(reg>>2)+4*(lane>>5)
#pragma unroll
  for (int j = 0; j < 4; ++j) {
    const int col = col0 + wn * 128 + j * 32 + r31;
    const float sc = scale[col];
    const float bs = bias[col];
#pragma unroll
    for (int i = 0; i < 4; ++i) {
      const int rbase = row0 + wm * 128 + i * 32 + 4 * half;
#pragma unroll
      for (int r = 0; r < 16; ++r) {
        const int row = rbase + (r & 3) + 8 * (r >> 2);
        float v = fminf(fmaxf((float)acc[i][j][r] * sc + bs, -1.0f), 1.0f);
        Hout[(size_t)row * HDIM + col] = (signed char)(int)rintf(v * 127.0f);
      }
    }
  }
}

// ---------------- GEMM2 (i8 MFMA, 256x256 tile, 4 waves @ 128x128) ---------
// r4-proven structure (273 us, MfmaUtil 44.4) + T1 swizzle. A: h1_i8
// [M][4096], B: state2_i8 [4096][4096] exact ternary. Fused OUT_DIM=1 head.

__global__ __launch_bounds__(256, 1)
void gemm2_kernel(const signed char* __restrict__ A,
                  const signed char* __restrict__ B,
                  const float* __restrict__ scale,   // softplus/127
                  const float* __restrict__ bias,
                  const float* __restrict__ w_out,
                  float* __restrict__ out) {
  constexpr int K = HDIM;
  extern __shared__ __align__(16) char smem[];
  signed char* const S = (signed char*)smem;  // As[2]: 0,32768  Bs[2]: 65536,98304

  const int tid = threadIdx.x;
  const int wave = tid >> 6;
  const int lane = tid & 63;
  const int r31 = lane & 31;
  const int half = lane >> 5;
  const int wm = wave >> 1;
  const int wn = wave & 1;
  int bx, by;
  swizzle_bid(bx, by);
  const int row0 = by * 256;
  const int col0 = bx * 256;

  i32x16 acc[4][4];
#pragma unroll
  for (int i = 0; i < 4; ++i)
#pragma unroll
    for (int j = 0; j < 4; ++j)
#pragma unroll
      for (int r = 0; r < 16; ++r) acc[i][j][r] = 0;

  const signed char* Ab = A + (size_t)row0 * K;
  const signed char* Bb = B + (size_t)col0 * K;

  auto stageA = [&](int buf, int k0) {
    signed char* As = S + buf * 32768;
#pragma unroll
    for (int rd = 0; rd < 8; ++rd) {
      const int p = rd * 256 + tid;
      const int r = p >> 3;
      const int c = (p & 7) ^ (r & 7);
      async_copy16(Ab + (size_t)r * K + k0 + c * 16, &As[(rd * 256 + wave * 64) * 16]);
    }
  };
  auto stageB = [&](int buf, int k0) {
    signed char* Bs = S + 65536 + buf * 32768;
#pragma unroll
    for (int rd = 0; rd < 8; ++rd) {
      const int p = rd * 256 + tid;
      const int r = p >> 3;
      const int c = (p & 7) ^ (r & 7);
      async_copy16(Bb + (size_t)r * K + k0 + c * 16, &Bs[(rd * 256 + wave * 64) * 16]);
    }
  };

#define G2_LOAD(SET, S_)                                                     \
  { const int c = (S_) * 2 + half;                                           \
    _Pragma("unroll") for (int i = 0; i < 4; ++i) {                          \
      const int ar = wm * 128 + i * 32 + r31;                                \
      const int cp = c ^ (ar & 7);                                           \
      aF[SET][i] = *(const i32x4*)&As[ar * 128 + cp * 16];                   \
      const int br = wn * 128 + i * 32 + r31;                                \
      const int cq = c ^ (br & 7);                                           \
      bF[SET][i] = *(const i32x4*)&Bs[br * 128 + cq * 16];                   \
    } }
#define G2_MMA(SET)                                                          \
  _Pragma("unroll") for (int i = 0; i < 4; ++i)                              \
    _Pragma("unroll") for (int j = 0; j < 4; ++j)                            \
      acc[i][j] = __builtin_amdgcn_mfma_i32_32x32x32_i8(aF[SET][i], bF[SET][j], acc[i][j], 0, 0, 0);

  constexpr int NT = K / 128;  // 32
  stageA(0, 0);
  stageB(0, 0);
  asm volatile("s_waitcnt vmcnt(0)" ::: "memory");
  BARRIER;

  for (int t = 0; t < NT; ++t) {
    const signed char* As = S + (t & 1) * 32768;
    const signed char* Bs = S + 65536 + (t & 1) * 32768;
    const int nb = (t + 1) & 1;
    const int nk0 = (t + 1) * 128;
    const bool pf = (t + 1 < NT);
    i32x4 aF[2][4], bF[2][4];

    G2_LOAD(0, 0)
    FENCE;
    G2_LOAD(1, 1)
    WAIT_LGKM(8);
    G2_MMA(0)
    if (pf) stageA(nb, nk0);
    G2_LOAD(0, 2)
    WAIT_LGKM(8);
    G2_MMA(1)
    if (pf) stageB(nb, nk0);
    G2_LOAD(1, 3)
    WAIT_LGKM(8);
    G2_MMA(0)
    WAIT_LGKM(0);
    G2_MMA(1)
    asm volatile("s_waitcnt vmcnt(0)" ::: "memory");
    BARRIER;
  }
#undef G2_LOAD
#undef G2_MMA

  // Fused head: out[row] += sum_col clip(acc*sc+bs)*w_out[col]
#pragma unroll
  for (int i = 0; i < 4; ++i) {
    float rs[16];
#pragma unroll
    for (int r = 0; r < 16; ++r) rs[r] = 0.0f;
#pragma unroll
    for (int j = 0; j < 4; ++j) {
      const int col = col0 + wn * 128 + j * 32 + r31;
      const float sc = scale[col];
      const float bs = bias[col];
      const float w = w_out[col];
#pragma unroll
      for (int r = 0; r < 16; ++r) {
        float v = fminf(fmaxf((float)acc[i][j][r] * sc + bs, -1.0f), 1.0f);
        rs[r] += v * w;
      }
    }
#pragma unroll
    for (int off = 1; off < 32; off <<= 1)
#pragma unroll
      for (int r = 0; r < 16; ++r)
        rs[r] += __shfl_xor(rs[r], off, 64);
    if (r31 == 0) {
      const int rbase = row0 + wm * 128 + i * 32 + 4 * half;
#pragma unroll
      for (int r = 0; r < 16; ++r)
        atomicAdd(&out[rbase + (r & 3) + 8 * (r >> 2)], rs[r]);
    }
  }
}

// ---------------- launch ----------------

extern "C" void kernel_launch(void* const* d_in, const int* in_sizes, int n_in,
                              void* d_out, int out_size, void* d_ws, size_t ws_size,
                              hipStream_t stream) {
  (void)in_sizes; (void)n_in; (void)ws_size;
  const float* x          = (const float*)d_in[0];
  const int*   state1     = (const int*)d_in[1];
  const float* log_scale1 = (const float*)d_in[2];
  const float* bias1      = (const float*)d_in[3];
  const int*   state2     = (const int*)d_in[4];
  const float* log_scale2 = (const float*)d_in[5];
  const float* bias2      = (const float*)d_in[6];
  const float* w_out      = (const float*)d_in[7];
  const float* b_out      = (const float*)d_in[8];
  float* out = (float*)d_out;

  // One-time: both GEMMs need 128 KB dynamic LDS (> default 64 KB cap).
  static int lds_attr_done = 0;
  if (!lds_attr_done) {
    hipFuncSetAttribute((const void*)gemm1_kernel,
                        hipFuncAttributeMaxDynamicSharedMemorySize, 131072);
    hipFuncSetAttribute((const void*)gemm2_kernel,
                        hipFuncAttributeMaxDynamicSharedMemorySize, 131072);
    lds_attr_done = 1;
  }

  char* ws = (char*)d_ws;
  signed char* xd  = (signed char*)ws; ws += (size_t)BATCH * K1;       // 32 MB (dual-plane A')
  signed char* s1d = (signed char*)ws; ws += (size_t)HDIM * K1;        // 8 MB (dual-plane B')
  signed char* s2q = (signed char*)ws; ws += (size_t)HDIM * HDIM;      // 16 MB
  signed char* h1q = (signed char*)ws; ws += (size_t)BATCH * HDIM;     // 64 MB
  float* scale1 = (float*)ws; ws += HDIM * sizeof(float);
  float* scale2 = (float*)ws; ws += HDIM * sizeof(float);

  const int nx4 = BATCH * IN_DIM / 4;
  const int n1_4 = HDIM * IN_DIM / 4;
  const int n2_4 = HDIM * HDIM / 4;

  cvt_x_dual_kernel<<<(nx4 + 255) / 256, 256, 0, stream>>>(x, (unsigned int*)xd, nx4);
  cvt_s_dual_kernel<<<(n1_4 + n2_4 + 255) / 256, 256, 0, stream>>>(
      state1, (unsigned int*)s1d, n1_4, state2, (unsigned int*)s2q, n2_4);
  const int init_n = (out_size > 2 * HDIM) ? out_size : 2 * HDIM;
  scales_init_kernel<<<(init_n + 255) / 256, 256, 0, stream>>>(
      log_scale1, scale1, log_scale2, scale2, b_out, out, out_size);

  dim3 grid(HDIM / 256, BATCH / 256);  // 16 x 64
  gemm1_kernel<<<grid, 256, 131072, stream>>>(xd, s1d, scale1, bias1, h1q);
  gemm2_kernel<<<grid, 256, 131072, stream>>>(h1q, s2q, scale2, bias2, w_out, out);
}

// Round 9
// 539.578 us; speedup vs baseline: 1.1469x; 1.0140x over previous
//
#include <hip/hip_runtime.h>
#include <stdint.h>

#define BATCH 16384
#define IN_DIM 1024
#define HDIM 4096
#define K1 (2 * IN_DIM)  // dual-plane K for gemm1: [a | b] concatenated

// Dual-plane x quantization (r8-proven, absmax 2.0e-3): a = rint(16x)
// (combined range +-7.97 sigma -> zero clipping), b = rint(127*(16x-a)) in
// [-64,64]. x ~= (127a+b)/2032, rep err <= 2.5e-4 (f16-parity).
#define XSTEP 16.0f
#define XDIV  2032.0f  // 127*16

typedef int i32x4 __attribute__((ext_vector_type(4)));
typedef int i32x16 __attribute__((ext_vector_type(16)));

typedef const __attribute__((address_space(1))) void* gas_ptr;
typedef __attribute__((address_space(3))) void* las_ptr;

__device__ __forceinline__ void async_copy16(const void* g, void* l) {
  __builtin_amdgcn_global_load_lds((gas_ptr)g, (las_ptr)l, 16, 0, 0);
}

#define FENCE asm volatile("" ::: "memory")
#define BARRIER do { FENCE; __builtin_amdgcn_s_barrier(); FENCE; } while (0)
#define WAIT_LGKM(N) do { asm volatile("s_waitcnt lgkmcnt(" #N ")" ::: "memory"); \
                          __builtin_amdgcn_sched_barrier(0); } while (0)

// r9: T1 XCD swizzle REVERTED. r8 A/B: swizzle routed row0/col0 through
// VGPRs (248 vs 200), gemm2 273->312 us, MfmaUtil 44->38. T1's mechanism
// needs HBM-bound re-fetch; this kernel is at 12% HBM with L2/L3-resident B.

// ---------------- prep kernels ----------------

// A' layout [M][2048] i8: row m = [a(k=0..1023) | b(k=0..1023)].
__global__ void cvt_x_dual_kernel(const float* __restrict__ in,
                                  unsigned int* __restrict__ outA, int n4) {
  int i = blockIdx.x * blockDim.x + threadIdx.x;
  if (i < n4) {
    const float4 v = ((const float4*)in)[i];
    const int m = i >> 8;       // 256 groups-of-4 per 1024-wide row
    const int g = i & 255;
    int a[4], b[4];
    const float xs[4] = {v.x, v.y, v.z, v.w};
#pragma unroll
    for (int t = 0; t < 4; ++t) {
      const float u = xs[t] * XSTEP;
      const float af = rintf(fminf(fmaxf(u, -127.0f), 127.0f));
      float bf = rintf((u - af) * 127.0f);
      bf = fminf(fmaxf(bf, -127.0f), 127.0f);
      a[t] = (int)af;
      b[t] = (int)bf;
    }
    outA[m * 512 + g] =
        (a[0] & 0xffu) | ((a[1] & 0xffu) << 8) | ((a[2] & 0xffu) << 16) | ((a[3] & 0xffu) << 24);
    outA[m * 512 + 256 + g] =
        (b[0] & 0xffu) | ((b[1] & 0xffu) << 8) | ((b[2] & 0xffu) << 16) | ((b[3] & 0xffu) << 24);
  }
}

// state1 -> B' [4096][2048] i8 = [127*s | s] (exact: 127*ternary in {0,+-127});
// state2 -> packed i8 (exact ternary).
__global__ void cvt_s_dual_kernel(const int* __restrict__ s1, unsigned int* __restrict__ o1, int n1_4,
                                  const int* __restrict__ s2, unsigned int* __restrict__ o2, int n2_4) {
  int i = blockIdx.x * blockDim.x + threadIdx.x;
  if (i < n1_4) {
    const int4 v = ((const int4*)s1)[i];
    const int n = i >> 8;
    const int g = i & 255;
    const int h0 = 127 * v.x, h1 = 127 * v.y, h2 = 127 * v.z, h3 = 127 * v.w;
    o1[n * 512 + g] =
        (h0 & 0xffu) | ((h1 & 0xffu) << 8) | ((h2 & 0xffu) << 16) | ((h3 & 0xffu) << 24);
    o1[n * 512 + 256 + g] =
        (v.x & 0xffu) | ((v.y & 0xffu) << 8) | ((v.z & 0xffu) << 16) | ((v.w & 0xffu) << 24);
  } else if (i < n1_4 + n2_4) {
    const int j = i - n1_4;
    const int4 v = ((const int4*)s2)[j];
    o2[j] = (v.x & 0xffu) | ((v.y & 0xffu) << 8) | ((v.z & 0xffu) << 16) | ((v.w & 0xffu) << 24);
  }
}

// scale1 = max(softplus(ls1),1e-4)/2032 (dual-plane dequant folded in)
// scale2 = max(softplus(ls2),1e-4)/127  (h1-i8 dequant folded in)
// out[i] = b_out[0] for ALL out_size rows (launch covers max(out_size, 2*HDIM)).
__global__ void scales_init_kernel(const float* __restrict__ ls1, float* __restrict__ s1,
                                   const float* __restrict__ ls2, float* __restrict__ s2,
                                   const float* __restrict__ b_out, float* __restrict__ out,
                                   int out_n) {
  int i = blockIdx.x * blockDim.x + threadIdx.x;
  if (i < out_n) out[i] = b_out[0];
  if (i < HDIM) {
    float l = ls1[i];
    float sp = (l > 20.0f) ? l : log1pf(expf(l));
    s1[i] = fmaxf(sp, 1e-4f) * (1.0f / XDIV);
  } else if (i < 2 * HDIM) {
    float l = ls2[i - HDIM];
    float sp = (l > 20.0f) ? l : log1pf(expf(l));
    s2[i - HDIM] = fmaxf(sp, 1e-4f) * (1.0f / 127.0f);
  }
}

// ---------------- GEMM1 (i8 MFMA, K=2048 dual-plane, r4 structure) ---------
// A: [a|b]_i8 [M][2048], B: [127*state1|state1]_i8 [4096][2048]. BK=128,
// NT=16, 4 waves @ 128x128, counted-lgkm register-dbuf pipeline, mid-tile
// staging, single vmcnt(0)+barrier per tile (r4-proven schedule verbatim).
// Epilogue: Hout = rint(127*clip(acc*s1/2032 + b1)) -> i8 for gemm2.

__global__ __launch_bounds__(256, 1)
void gemm1_kernel(const signed char* __restrict__ A,
                  const signed char* __restrict__ B,
                  const float* __restrict__ scale,   // softplus/2032
                  const float* __restrict__ bias,
                  signed char* __restrict__ Hout) {
  constexpr int K = K1;  // 2048
  extern __shared__ __align__(16) char smem[];
  signed char* const S = (signed char*)smem;  // As[2]: 0,32768  Bs[2]: 65536,98304

  const int tid = threadIdx.x;
  const int wave = tid >> 6;
  const int lane = tid & 63;
  const int r31 = lane & 31;
  const int half = lane >> 5;
  const int wm = wave >> 1;
  const int wn = wave & 1;
  const int row0 = blockIdx.y * 256;
  const int col0 = blockIdx.x * 256;

  i32x16 acc[4][4];
#pragma unroll
  for (int i = 0; i < 4; ++i)
#pragma unroll
    for (int j = 0; j < 4; ++j)
#pragma unroll
      for (int r = 0; r < 16; ++r) acc[i][j][r] = 0;

  const signed char* Ab = A + (size_t)row0 * K;
  const signed char* Bb = B + (size_t)col0 * K;

  auto stageA = [&](int buf, int k0) {
    signed char* As = S + buf * 32768;
#pragma unroll
    for (int rd = 0; rd < 8; ++rd) {
      const int p = rd * 256 + tid;
      const int r = p >> 3;
      const int c = (p & 7) ^ (r & 7);
      async_copy16(Ab + (size_t)r * K + k0 + c * 16, &As[(rd * 256 + wave * 64) * 16]);
    }
  };
  auto stageB = [&](int buf, int k0) {
    signed char* Bs = S + 65536 + buf * 32768;
#pragma unroll
    for (int rd = 0; rd < 8; ++rd) {
      const int p = rd * 256 + tid;
      const int r = p >> 3;
      const int c = (p & 7) ^ (r & 7);
      async_copy16(Bb + (size_t)r * K + k0 + c * 16, &Bs[(rd * 256 + wave * 64) * 16]);
    }
  };

#define G1_LOAD(SET, S_)                                                     \
  { const int c = (S_) * 2 + half;                                           \
    _Pragma("unroll") for (int i = 0; i < 4; ++i) {                          \
      const int ar = wm * 128 + i * 32 + r31;                                \
      const int cp = c ^ (ar & 7);                                           \
      aF[SET][i] = *(const i32x4*)&As[ar * 128 + cp * 16];                   \
      const int br = wn * 128 + i * 32 + r31;                                \
      const int cq = c ^ (br & 7);                                           \
      bF[SET][i] = *(const i32x4*)&Bs[br * 128 + cq * 16];                   \
    } }
#define G1_MMA(SET)                                                          \
  _Pragma("unroll") for (int i = 0; i < 4; ++i)                              \
    _Pragma("unroll") for (int j = 0; j < 4; ++j)                            \
      acc[i][j] = __builtin_amdgcn_mfma_i32_32x32x32_i8(aF[SET][i], bF[SET][j], acc[i][j], 0, 0, 0);

  constexpr int NT = K / 128;  // 16
  stageA(0, 0);
  stageB(0, 0);
  asm volatile("s_waitcnt vmcnt(0)" ::: "memory");
  BARRIER;

  for (int t = 0; t < NT; ++t) {
    const signed char* As = S + (t & 1) * 32768;
    const signed char* Bs = S + 65536 + (t & 1) * 32768;
    const int nb = (t + 1) & 1;
    const int nk0 = (t + 1) * 128;
    const bool pf = (t + 1 < NT);
    i32x4 aF[2][4], bF[2][4];

    G1_LOAD(0, 0)
    FENCE;
    G1_LOAD(1, 1)
    WAIT_LGKM(8);
    G1_MMA(0)
    if (pf) stageA(nb, nk0);
    G1_LOAD(0, 2)
    WAIT_LGKM(8);
    G1_MMA(1)
    if (pf) stageB(nb, nk0);
    G1_LOAD(1, 3)
    WAIT_LGKM(8);
    G1_MMA(0)
    WAIT_LGKM(0);
    G1_MMA(1)
    asm volatile("s_waitcnt vmcnt(0)" ::: "memory");
    BARRIER;
  }
#undef G1_LOAD
#undef G1_MMA

  // C/D 32x32 layout: col = lane&31, row = (reg&3)+8*(reg>>2)+4*(lane>>5)
#pragma unroll
  for (int j = 0; j < 4; ++j) {
    const int col = col0 + wn * 128 + j * 32 + r31;
    const float sc = scale[col];
    const float bs = bias[col];
#pragma unroll
    for (int i = 0; i < 4; ++i) {
      const int rbase = row0 + wm * 128 + i * 32 + 4 * half;
#pragma unroll
      for (int r = 0; r < 16; ++r) {
        const int row = rbase + (r & 3) + 8 * (r >> 2);
        float v = fminf(fmaxf((float)acc[i][j][r] * sc + bs, -1.0f), 1.0f);
        Hout[(size_t)row * HDIM + col] = (signed char)(int)rintf(v * 127.0f);
      }
    }
  }
}

// ---------------- GEMM2 (i8 MFMA, 256x256 tile, 4 waves @ 128x128) ---------
// r4-proven structure VERBATIM (273 us, MfmaUtil 44.4, VGPR 200). A: h1_i8
// [M][4096], B: state2_i8 [4096][4096] exact ternary. Fused OUT_DIM=1 head.

__global__ __launch_bounds__(256, 1)
void gemm2_kernel(const signed char* __restrict__ A,
                  const signed char* __restrict__ B,
                  const float* __restrict__ scale,   // softplus/127
                  const float* __restrict__ bias,
                  const float* __restrict__ w_out,
                  float* __restrict__ out) {
  constexpr int K = HDIM;
  extern __shared__ __align__(16) char smem[];
  signed char* const S = (signed char*)smem;  // As[2]: 0,32768  Bs[2]: 65536,98304

  const int tid = threadIdx.x;
  const int wave = tid >> 6;
  const int lane = tid & 63;
  const int r31 = lane & 31;
  const int half = lane >> 5;
  const int wm = wave >> 1;
  const int wn = wave & 1;
  const int row0 = blockIdx.y * 256;
  const int col0 = blockIdx.x * 256;

  i32x16 acc[4][4];
#pragma unroll
  for (int i = 0; i < 4; ++i)
#pragma unroll
    for (int j = 0; j < 4; ++j)
#pragma unroll
      for (int r = 0; r < 16; ++r) acc[i][j][r] = 0;

  const signed char* Ab = A + (size_t)row0 * K;
  const signed char* Bb = B + (size_t)col0 * K;

  auto stageA = [&](int buf, int k0) {
    signed char* As = S + buf * 32768;
#pragma unroll
    for (int rd = 0; rd < 8; ++rd) {
      const int p = rd * 256 + tid;
      const int r = p >> 3;
      const int c = (p & 7) ^ (r & 7);
      async_copy16(Ab + (size_t)r * K + k0 + c * 16, &As[(rd * 256 + wave * 64) * 16]);
    }
  };
  auto stageB = [&](int buf, int k0) {
    signed char* Bs = S + 65536 + buf * 32768;
#pragma unroll
    for (int rd = 0; rd < 8; ++rd) {
      const int p = rd * 256 + tid;
      const int r = p >> 3;
      const int c = (p & 7) ^ (r & 7);
      async_copy16(Bb + (size_t)r * K + k0 + c * 16, &Bs[(rd * 256 + wave * 64) * 16]);
    }
  };

#define G2_LOAD(SET, S_)                                                     \
  { const int c = (S_) * 2 + half;                                           \
    _Pragma("unroll") for (int i = 0; i < 4; ++i) {                          \
      const int ar = wm * 128 + i * 32 + r31;                                \
      const int cp = c ^ (ar & 7);                                           \
      aF[SET][i] = *(const i32x4*)&As[ar * 128 + cp * 16];                   \
      const int br = wn * 128 + i * 32 + r31;                                \
      const int cq = c ^ (br & 7);                                           \
      bF[SET][i] = *(const i32x4*)&Bs[br * 128 + cq * 16];                   \
    } }
#define G2_MMA(SET)                                                          \
  _Pragma("unroll") for (int i = 0; i < 4; ++i)                              \
    _Pragma("unroll") for (int j = 0; j < 4; ++j)                            \
      acc[i][j] = __builtin_amdgcn_mfma_i32_32x32x32_i8(aF[SET][i], bF[SET][j], acc[i][j], 0, 0, 0);

  constexpr int NT = K / 128;  // 32
  stageA(0, 0);
  stageB(0, 0);
  asm volatile("s_waitcnt vmcnt(0)" ::: "memory");
  BARRIER;

  for (int t = 0; t < NT; ++t) {
    const signed char* As = S + (t & 1) * 32768;
    const signed char* Bs = S + 65536 + (t & 1) * 32768;
    const int nb = (t + 1) & 1;
    const int nk0 = (t + 1) * 128;
    const bool pf = (t + 1 < NT);
    i32x4 aF[2][4], bF[2][4];

    G2_LOAD(0, 0)
    FENCE;
    G2_LOAD(1, 1)
    WAIT_LGKM(8);
    G2_MMA(0)
    if (pf) stageA(nb, nk0);
    G2_LOAD(0, 2)
    WAIT_LGKM(8);
    G2_MMA(1)
    if (pf) stageB(nb, nk0);
    G2_LOAD(1, 3)
    WAIT_LGKM(8);
    G2_MMA(0)
    WAIT_LGKM(0);
    G2_MMA(1)
    asm volatile("s_waitcnt vmcnt(0)" ::: "memory");
    BARRIER;
  }
#undef G2_LOAD
#undef G2_MMA

  // Fused head: out[row] += sum_col clip(acc*sc+bs)*w_out[col]
#pragma unroll
  for (int i = 0; i < 4; ++i) {
    float rs[16];
#pragma unroll
    for (int r = 0; r < 16; ++r) rs[r] = 0.0f;
#pragma unroll
    for (int j = 0; j < 4; ++j) {
      const int col = col0 + wn * 128 + j * 32 + r31;
      const float sc = scale[col];
      const float bs = bias[col];
      const float w = w_out[col];
#pragma unroll
      for (int r = 0; r < 16; ++r) {
        float v = fminf(fmaxf((float)acc[i][j][r] * sc + bs, -1.0f), 1.0f);
        rs[r] += v * w;
      }
    }
#pragma unroll
    for (int off = 1; off < 32; off <<= 1)
#pragma unroll
      for (int r = 0; r < 16; ++r)
        rs[r] += __shfl_xor(rs[r], off, 64);
    if (r31 == 0) {
      const int rbase = row0 + wm * 128 + i * 32 + 4 * half;
#pragma unroll
      for (int r = 0; r < 16; ++r)
        atomicAdd(&out[rbase + (r & 3) + 8 * (r >> 2)], rs[r]);
    }
  }
}

// ---------------- launch ----------------

extern "C" void kernel_launch(void* const* d_in, const int* in_sizes, int n_in,
                              void* d_out, int out_size, void* d_ws, size_t ws_size,
                              hipStream_t stream) {
  (void)in_sizes; (void)n_in; (void)ws_size;
  const float* x          = (const float*)d_in[0];
  const int*   state1     = (const int*)d_in[1];
  const float* log_scale1 = (const float*)d_in[2];
  const float* bias1      = (const float*)d_in[3];
  const int*   state2     = (const int*)d_in[4];
  const float* log_scale2 = (const float*)d_in[5];
  const float* bias2      = (const float*)d_in[6];
  const float* w_out      = (const float*)d_in[7];
  const float* b_out      = (const float*)d_in[8];
  float* out = (float*)d_out;

  // One-time: both GEMMs need 128 KB dynamic LDS (> default 64 KB cap).
  static int lds_attr_done = 0;
  if (!lds_attr_done) {
    hipFuncSetAttribute((const void*)gemm1_kernel,
                        hipFuncAttributeMaxDynamicSharedMemorySize, 131072);
    hipFuncSetAttribute((const void*)gemm2_kernel,
                        hipFuncAttributeMaxDynamicSharedMemorySize, 131072);
    lds_attr_done = 1;
  }

  char* ws = (char*)d_ws;
  signed char* xd  = (signed char*)ws; ws += (size_t)BATCH * K1;       // 32 MB (dual-plane A')
  signed char* s1d = (signed char*)ws; ws += (size_t)HDIM * K1;        // 8 MB (dual-plane B')
  signed char* s2q = (signed char*)ws; ws += (size_t)HDIM * HDIM;      // 16 MB
  signed char* h1q = (signed char*)ws; ws += (size_t)BATCH * HDIM;     // 64 MB
  float* scale1 = (float*)ws; ws += HDIM * sizeof(float);
  float* scale2 = (float*)ws; ws += HDIM * sizeof(float);

  const int nx4 = BATCH * IN_DIM / 4;
  const int n1_4 = HDIM * IN_DIM / 4;
  const int n2_4 = HDIM * HDIM / 4;

  cvt_x_dual_kernel<<<(nx4 + 255) / 256, 256, 0, stream>>>(x, (unsigned int*)xd, nx4);
  cvt_s_dual_kernel<<<(n1_4 + n2_4 + 255) / 256, 256, 0, stream>>>(
      state1, (unsigned int*)s1d, n1_4, state2, (unsigned int*)s2q, n2_4);
  const int init_n = (out_size > 2 * HDIM) ? out_size : 2 * HDIM;
  scales_init_kernel<<<(init_n + 255) / 256, 256, 0, stream>>>(
      log_scale1, scale1, log_scale2, scale2, b_out, out, out_size);

  dim3 grid(HDIM / 256, BATCH / 256);  // 16 x 64
  gemm1_kernel<<<grid, 256, 131072, stream>>>(xd, s1d, scale1, bias1, h1q);
  gemm2_kernel<<<grid, 256, 131072, stream>>>(h1q, s2q, scale2, bias2, w_out, out);
}